// Round 8
// baseline (522.187 us; speedup 1.0000x reference)
//
#include <hip/hip_runtime.h>

// NeighborList: N atoms, minimum-image convention, cutoff 5.0.
// Output layout (all float32): pairs[2*P], deltas[P*3], distances[P], n_pairs[1]
// Ordering must match jnp.nonzero(mask.ravel()) -> ascending flat index i*N+j.
//
// SINGLE dispatch, no cooperative launch (cg grid.sync measured 100+us -- R3).
// Protocol: wave = row; block b = rows 4b..4b+3. Each block publishes a
// magic-tagged 64-bit count aggregate; block 0 wave 0 (heaviest row, finishes
// last anyway) scans the 1024 aggregates and publishes per-block exclusive
// prefixes; every wave spin-loads only its own block's prefix. Per-chunk hit
// masks stay in REGISTERS across count->fill (lane c holds chunk c's mask).
// Deadlock-safe: 1024 blocks x 256 thr at __launch_bounds__(256,4) are all
// co-resident (4 blocks/CU, <=128 VGPR, ~16B LDS). Magic tag makes the
// 0xAA-poisoned workspace read as "not ready" -- no zeroing pass needed.

#define CUT2 25.0f
#define MAGIC_HI 0x5AFEC0DEu

__device__ __forceinline__ void load_box_inv(const float* __restrict__ box,
                                             float B[3][3], float Binv[3][3]) {
    #pragma unroll
    for (int r = 0; r < 3; ++r)
        #pragma unroll
        for (int c = 0; c < 3; ++c)
            B[r][c] = box[r * 3 + c];

    float a00 = B[0][0], a01 = B[0][1], a02 = B[0][2];
    float a10 = B[1][0], a11 = B[1][1], a12 = B[1][2];
    float a20 = B[2][0], a21 = B[2][1], a22 = B[2][2];

    float adj00 =  (a11 * a22 - a12 * a21);
    float adj01 = -(a01 * a22 - a02 * a21);
    float adj02 =  (a01 * a12 - a02 * a11);
    float adj10 = -(a10 * a22 - a12 * a20);
    float adj11 =  (a00 * a22 - a02 * a20);
    float adj12 = -(a00 * a12 - a02 * a10);
    float adj20 =  (a10 * a21 - a11 * a20);
    float adj21 = -(a00 * a21 - a01 * a20);
    float adj22 =  (a00 * a11 - a01 * a10);

    float det = a00 * adj00 + a01 * adj10 + a02 * adj20;

    // per-entry division: for diagonal box this rounds identically to
    // LAPACK's 1/pivot (single rounding of the exact quotient).
    Binv[0][0] = __fdiv_rn(adj00, det); Binv[0][1] = __fdiv_rn(adj01, det); Binv[0][2] = __fdiv_rn(adj02, det);
    Binv[1][0] = __fdiv_rn(adj10, det); Binv[1][1] = __fdiv_rn(adj11, det); Binv[1][2] = __fdiv_rn(adj12, det);
    Binv[2][0] = __fdiv_rn(adj20, det); Binv[2][1] = __fdiv_rn(adj21, det); Binv[2][2] = __fdiv_rn(adj22, det);
}

// General triclinic path. Replicates numpy rounding exactly (no FMA):
// delta = pos_i - pos_j; frac = delta @ Binv; delta -= rint(frac) @ B; d2.
__device__ __forceinline__ void min_image(float xi, float yi, float zi,
                                          float xj, float yj, float zj,
                                          const float B[3][3], const float Binv[3][3],
                                          float& dx, float& dy, float& dz, float& d2) {
    dx = __fsub_rn(xi, xj);
    dy = __fsub_rn(yi, yj);
    dz = __fsub_rn(zi, zj);

    float f0 = __fadd_rn(__fadd_rn(__fmul_rn(dx, Binv[0][0]), __fmul_rn(dy, Binv[1][0])), __fmul_rn(dz, Binv[2][0]));
    float f1 = __fadd_rn(__fadd_rn(__fmul_rn(dx, Binv[0][1]), __fmul_rn(dy, Binv[1][1])), __fmul_rn(dz, Binv[2][1]));
    float f2 = __fadd_rn(__fadd_rn(__fmul_rn(dx, Binv[0][2]), __fmul_rn(dy, Binv[1][2])), __fmul_rn(dz, Binv[2][2]));

    float r0 = rintf(f0), r1 = rintf(f1), r2 = rintf(f2);

    float c0 = __fadd_rn(__fadd_rn(__fmul_rn(r0, B[0][0]), __fmul_rn(r1, B[1][0])), __fmul_rn(r2, B[2][0]));
    float c1 = __fadd_rn(__fadd_rn(__fmul_rn(r0, B[0][1]), __fmul_rn(r1, B[1][1])), __fmul_rn(r2, B[2][1]));
    float c2 = __fadd_rn(__fadd_rn(__fmul_rn(r0, B[0][2]), __fmul_rn(r1, B[1][2])), __fmul_rn(r2, B[2][2]));

    dx = __fsub_rn(dx, c0);
    dy = __fsub_rn(dy, c1);
    dz = __fsub_rn(dz, c2);

    d2 = __fadd_rn(__fadd_rn(__fmul_rn(dx, dx), __fmul_rn(dy, dy)), __fmul_rn(dz, dz));
}

// Diagonal-box fast path: same values as the general path when all
// off-diagonal box entries are zero (cross terms are +-0; dropping them can
// only flip sign of an exact zero, which d2 and the wrap subtraction erase).
__device__ __forceinline__ void min_image_diag(float xi, float yi, float zi,
                                               float xj, float yj, float zj,
                                               float b0, float b1, float b2,
                                               float ib0, float ib1, float ib2,
                                               float& dx, float& dy, float& dz, float& d2) {
    dx = __fsub_rn(xi, xj);
    dy = __fsub_rn(yi, yj);
    dz = __fsub_rn(zi, zj);
    float r0 = rintf(__fmul_rn(dx, ib0));
    float r1 = rintf(__fmul_rn(dy, ib1));
    float r2 = rintf(__fmul_rn(dz, ib2));
    dx = __fsub_rn(dx, __fmul_rn(r0, b0));
    dy = __fsub_rn(dy, __fmul_rn(r1, b1));
    dz = __fsub_rn(dz, __fmul_rn(r2, b2));
    d2 = __fadd_rn(__fadd_rn(__fmul_rn(dx, dx), __fmul_rn(dy, dy)), __fmul_rn(dz, dz));
}

// Count hits for row i (j > i); lane c of the wave accumulates chunk c's
// 64-bit hit mask in mymask (kept in a register for the fill phase).
template <bool DIAG>
__device__ __forceinline__ int count_row_reg(int i, int lane,
                                             const float* __restrict__ pos,
                                             const float B[3][3], const float Binv[3][3],
                                             int nchunks, unsigned long long& mymask) {
    float xi = pos[3 * i + 0], yi = pos[3 * i + 1], zi = pos[3 * i + 2];
    float b0 = B[0][0], b1 = B[1][1], b2 = B[2][2];
    float ib0 = Binv[0][0], ib1 = Binv[1][1], ib2 = Binv[2][2];
    int c0 = i >> 6;
    int cnt = 0;
    mymask = 0ull;

    // Diagonal chunk: needs the j>i predicate.
    {
        int j = (c0 << 6) + lane;
        bool hit = false;
        if (j > i) {
            float dx, dy, dz, d2;
            if (DIAG)
                min_image_diag(xi, yi, zi, pos[3 * j], pos[3 * j + 1], pos[3 * j + 2],
                               b0, b1, b2, ib0, ib1, ib2, dx, dy, dz, d2);
            else
                min_image(xi, yi, zi, pos[3 * j], pos[3 * j + 1], pos[3 * j + 2],
                          B, Binv, dx, dy, dz, d2);
            hit = (d2 < CUT2);
        }
        unsigned long long m = __ballot(hit);
        if (lane == c0) mymask = m;
        cnt += __popcll(m);
    }

    // Remaining chunks: all j > i. Unroll x4 for ILP.
    int c = c0 + 1;
    for (; c + 4 <= nchunks; c += 4) {
        int j0 = (c << 6) + lane;
        float dx0, dy0, dz0, d20, dx1, dy1, dz1, d21;
        float dx2, dy2, dz2, d22, dx3, dy3, dz3, d23;
        if (DIAG) {
            min_image_diag(xi, yi, zi, pos[3 * j0 +   0], pos[3 * j0 +   1], pos[3 * j0 +   2], b0, b1, b2, ib0, ib1, ib2, dx0, dy0, dz0, d20);
            min_image_diag(xi, yi, zi, pos[3 * j0 + 192], pos[3 * j0 + 193], pos[3 * j0 + 194], b0, b1, b2, ib0, ib1, ib2, dx1, dy1, dz1, d21);
            min_image_diag(xi, yi, zi, pos[3 * j0 + 384], pos[3 * j0 + 385], pos[3 * j0 + 386], b0, b1, b2, ib0, ib1, ib2, dx2, dy2, dz2, d22);
            min_image_diag(xi, yi, zi, pos[3 * j0 + 576], pos[3 * j0 + 577], pos[3 * j0 + 578], b0, b1, b2, ib0, ib1, ib2, dx3, dy3, dz3, d23);
        } else {
            min_image(xi, yi, zi, pos[3 * j0 +   0], pos[3 * j0 +   1], pos[3 * j0 +   2], B, Binv, dx0, dy0, dz0, d20);
            min_image(xi, yi, zi, pos[3 * j0 + 192], pos[3 * j0 + 193], pos[3 * j0 + 194], B, Binv, dx1, dy1, dz1, d21);
            min_image(xi, yi, zi, pos[3 * j0 + 384], pos[3 * j0 + 385], pos[3 * j0 + 386], B, Binv, dx2, dy2, dz2, d22);
            min_image(xi, yi, zi, pos[3 * j0 + 576], pos[3 * j0 + 577], pos[3 * j0 + 578], B, Binv, dx3, dy3, dz3, d23);
        }
        unsigned long long m0 = __ballot(d20 < CUT2);
        unsigned long long m1 = __ballot(d21 < CUT2);
        unsigned long long m2 = __ballot(d22 < CUT2);
        unsigned long long m3 = __ballot(d23 < CUT2);
        if (lane == c)     mymask = m0;
        if (lane == c + 1) mymask = m1;
        if (lane == c + 2) mymask = m2;
        if (lane == c + 3) mymask = m3;
        cnt += __popcll(m0) + __popcll(m1) + __popcll(m2) + __popcll(m3);
    }
    for (; c < nchunks; ++c) {
        int j = (c << 6) + lane;
        float dx, dy, dz, d2;
        if (DIAG)
            min_image_diag(xi, yi, zi, pos[3 * j], pos[3 * j + 1], pos[3 * j + 2],
                           b0, b1, b2, ib0, ib1, ib2, dx, dy, dz, d2);
        else
            min_image(xi, yi, zi, pos[3 * j], pos[3 * j + 1], pos[3 * j + 2],
                      B, Binv, dx, dy, dz, d2);
        unsigned long long m = __ballot(d2 < CUT2);
        if (lane == c) mymask = m;
        cnt += __popcll(m);
    }
    return cnt;
}

__global__ void __launch_bounds__(256, 4)
nl_onepass(const float* __restrict__ pos, const float* __restrict__ box,
           float* __restrict__ out,
           unsigned long long* __restrict__ bstate,   // per-block count aggregate
           unsigned long long* __restrict__ pstate,   // per-block exclusive prefix
           int N, int P) {
    int b = blockIdx.x;
    int wid = threadIdx.x >> 6;          // 0..3
    int lane = threadIdx.x & 63;
    int row = 4 * b + wid;               // one wave per row
    int nblocks = gridDim.x;             // N/4
    int nchunks = N >> 6;
    int tid = b * blockDim.x + threadIdx.x;
    int nthreads = nblocks * blockDim.x;

    __shared__ int scnt[4];

    // ---- pad: pairs = -1, rest = 0 (ordered before all fills by the
    //      bstate release -> scanner acquire -> pstate release -> fill chain)
    int total = 6 * P + 1;
    for (int k = tid; k < total; k += nthreads)
        out[k] = (k < 2 * P) ? -1.0f : 0.0f;

    float B[3][3], Binv[3][3];
    load_box_inv(box, B, Binv);
    bool diag = (B[0][1] == 0.0f) & (B[0][2] == 0.0f) & (B[1][0] == 0.0f) &
                (B[1][2] == 0.0f) & (B[2][0] == 0.0f) & (B[2][1] == 0.0f);

    // ---- count (masks in registers) ----
    unsigned long long mymask;
    int cnt;
    if (diag)
        cnt = count_row_reg<true>(row, lane, pos, B, Binv, nchunks, mymask);
    else
        cnt = count_row_reg<false>(row, lane, pos, B, Binv, nchunks, mymask);

    if (lane == 0) scnt[wid] = cnt;
    __syncthreads();                     // also drains this block's pad stores

    // ---- publish block aggregate (magic-tagged; 0xAA poison reads invalid)
    if (threadIdx.x == 0) {
        unsigned long long agg = ((unsigned long long)MAGIC_HI << 32) |
                                 (unsigned)(scnt[0] + scnt[1] + scnt[2] + scnt[3]);
        __hip_atomic_store(&bstate[b], agg, __ATOMIC_RELEASE, __HIP_MEMORY_SCOPE_AGENT);
    }

    // ---- scanner: block 0, wave 0 (heaviest row -> finishes among last,
    //      so its polls mostly hit ready aggregates)
    if (b == 0 && wid == 0) {
        int carry = 0;
        for (int base = 0; base < nblocks; base += 64) {
            int idx = base + lane;
            bool need = idx < nblocks;
            unsigned long long v = 0;
            do {
                if (need)
                    v = __hip_atomic_load(&bstate[idx], __ATOMIC_ACQUIRE,
                                          __HIP_MEMORY_SCOPE_AGENT);
            } while (__ballot(need && (unsigned)(v >> 32) != MAGIC_HI));
            int val = need ? (int)(v & 0xffffffffu) : 0;
            int incl = val;
            #pragma unroll
            for (int d = 1; d < 64; d <<= 1) {
                int t = __shfl_up(incl, d);
                if (lane >= d) incl += t;
            }
            int excl = incl - val + carry;
            if (need) {
                unsigned long long pv = ((unsigned long long)MAGIC_HI << 32) |
                                        (unsigned)excl;
                __hip_atomic_store(&pstate[idx], pv, __ATOMIC_RELEASE,
                                   __HIP_MEMORY_SCOPE_AGENT);
            }
            carry += __shfl(incl, 63);   // chunk total
        }
        if (lane == 0)
            out[6 * (size_t)P] = (float)carry;   // n_pairs (pads all done: saw every bstate)
    }

    // ---- all waves: wait for own block's exclusive prefix ----
    unsigned long long pv;
    for (;;) {
        pv = __hip_atomic_load(&pstate[b], __ATOMIC_ACQUIRE, __HIP_MEMORY_SCOPE_AGENT);
        if ((unsigned)(pv >> 32) == MAGIC_HI) break;
        __builtin_amdgcn_s_sleep(1);
    }
    int base_slot = (int)(pv & 0xffffffffu);
    #pragma unroll
    for (int t = 0; t < 4; ++t)
        if (t < wid) base_slot += scnt[t];   // rows 4b..row-1

    // ---- ordered fill from in-register masks ----
    float xi = pos[3 * row + 0], yi = pos[3 * row + 1], zi = pos[3 * row + 2];
    int c0 = row >> 6;
    int base = base_slot;
    for (int cc = c0; cc < nchunks; ++cc) {
        unsigned long long m = __shfl(mymask, cc);
        if (m != 0ull) {
            if ((m >> lane) & 1ull) {
                int j = (cc << 6) + lane;
                float dx, dy, dz, d2;
                min_image(xi, yi, zi, pos[3 * j + 0], pos[3 * j + 1], pos[3 * j + 2],
                          B, Binv, dx, dy, dz, d2);
                int slot = base + __popcll(m & ((1ull << lane) - 1ull));
                if (slot < P) {
                    out[slot] = (float)row;                  // pair_i
                    out[P + slot] = (float)j;                // pair_j
                    size_t db = 2 * (size_t)P + 3 * (size_t)slot;
                    out[db + 0] = dx;
                    out[db + 1] = dy;
                    out[db + 2] = dz;
                    out[5 * (size_t)P + slot] = sqrtf(d2);   // distance
                }
            }
            base += __popcll(m);
        }
    }
}

extern "C" void kernel_launch(void* const* d_in, const int* in_sizes, int n_in,
                              void* d_out, int out_size, void* d_ws, size_t ws_size,
                              hipStream_t stream) {
    const float* pos = (const float*)d_in[0];
    const float* box = (const float*)d_in[1];
    float* out = (float*)d_out;

    int N = in_sizes[0] / 3;          // 4096
    int P = (out_size - 1) / 6;       // 131072
    int nblocks = N / 4;              // 1024 (one wave per row, 4 rows/block)

    // ws layout: bstate[nblocks] u64 | pstate[nblocks] u64
    unsigned long long* bstate = (unsigned long long*)d_ws;
    unsigned long long* pstate = bstate + nblocks;

    nl_onepass<<<nblocks, 256, 0, stream>>>(pos, box, out, bstate, pstate, N, P);
}

// Round 9
// 86.984 us; speedup vs baseline: 6.0032x; 6.0032x over previous
//
#include <hip/hip_runtime.h>

// NeighborList: N atoms, minimum-image convention, cutoff 5.0.
// Output layout (all float32): pairs[2*P], deltas[P*3], distances[P], n_pairs[1]
// Ordering must match jnp.nonzero(mask.ravel()) -> ascending flat index i*N+j.
//
// THREE dispatches. Hard-won structure notes:
//  - NO intra-kernel global sync: cg grid.sync = 140us (R3), hand-rolled
//    acquire/release spin = 535us (R8) on this 8-XCD chip.
//  - K0: transpose positions to SoA X/Y/Z in ws. Stride-3 AoS gather made
//    each chunk touch 36 L1 lines; SoA touches 12 (3x cut in the L1 term).
//  - K1: pad output + per-row count + per-chunk 64-bit hit masks (1 wave/row).
//  - K2: per-wave int4 prefix over counts[] + ordered fill from masks.
//  - Diagonal-box fast path (values identical: dropped cross terms are +-0).

#define CUT2 25.0f

__device__ __forceinline__ void load_box_inv(const float* __restrict__ box,
                                             float B[3][3], float Binv[3][3]) {
    #pragma unroll
    for (int r = 0; r < 3; ++r)
        #pragma unroll
        for (int c = 0; c < 3; ++c)
            B[r][c] = box[r * 3 + c];

    float a00 = B[0][0], a01 = B[0][1], a02 = B[0][2];
    float a10 = B[1][0], a11 = B[1][1], a12 = B[1][2];
    float a20 = B[2][0], a21 = B[2][1], a22 = B[2][2];

    float adj00 =  (a11 * a22 - a12 * a21);
    float adj01 = -(a01 * a22 - a02 * a21);
    float adj02 =  (a01 * a12 - a02 * a11);
    float adj10 = -(a10 * a22 - a12 * a20);
    float adj11 =  (a00 * a22 - a02 * a20);
    float adj12 = -(a00 * a12 - a02 * a10);
    float adj20 =  (a10 * a21 - a11 * a20);
    float adj21 = -(a00 * a21 - a01 * a20);
    float adj22 =  (a00 * a11 - a01 * a10);

    float det = a00 * adj00 + a01 * adj10 + a02 * adj20;

    // per-entry division: for diagonal box this rounds identically to
    // LAPACK's 1/pivot (single rounding of the exact quotient).
    Binv[0][0] = __fdiv_rn(adj00, det); Binv[0][1] = __fdiv_rn(adj01, det); Binv[0][2] = __fdiv_rn(adj02, det);
    Binv[1][0] = __fdiv_rn(adj10, det); Binv[1][1] = __fdiv_rn(adj11, det); Binv[1][2] = __fdiv_rn(adj12, det);
    Binv[2][0] = __fdiv_rn(adj20, det); Binv[2][1] = __fdiv_rn(adj21, det); Binv[2][2] = __fdiv_rn(adj22, det);
}

// General triclinic path. Replicates numpy rounding exactly (no FMA):
// delta = pos_i - pos_j; frac = delta @ Binv; delta -= rint(frac) @ B; d2.
__device__ __forceinline__ void min_image(float xi, float yi, float zi,
                                          float xj, float yj, float zj,
                                          const float B[3][3], const float Binv[3][3],
                                          float& dx, float& dy, float& dz, float& d2) {
    dx = __fsub_rn(xi, xj);
    dy = __fsub_rn(yi, yj);
    dz = __fsub_rn(zi, zj);

    float f0 = __fadd_rn(__fadd_rn(__fmul_rn(dx, Binv[0][0]), __fmul_rn(dy, Binv[1][0])), __fmul_rn(dz, Binv[2][0]));
    float f1 = __fadd_rn(__fadd_rn(__fmul_rn(dx, Binv[0][1]), __fmul_rn(dy, Binv[1][1])), __fmul_rn(dz, Binv[2][1]));
    float f2 = __fadd_rn(__fadd_rn(__fmul_rn(dx, Binv[0][2]), __fmul_rn(dy, Binv[1][2])), __fmul_rn(dz, Binv[2][2]));

    float r0 = rintf(f0), r1 = rintf(f1), r2 = rintf(f2);

    float c0 = __fadd_rn(__fadd_rn(__fmul_rn(r0, B[0][0]), __fmul_rn(r1, B[1][0])), __fmul_rn(r2, B[2][0]));
    float c1 = __fadd_rn(__fadd_rn(__fmul_rn(r0, B[0][1]), __fmul_rn(r1, B[1][1])), __fmul_rn(r2, B[2][1]));
    float c2 = __fadd_rn(__fadd_rn(__fmul_rn(r0, B[0][2]), __fmul_rn(r1, B[1][2])), __fmul_rn(r2, B[2][2]));

    dx = __fsub_rn(dx, c0);
    dy = __fsub_rn(dy, c1);
    dz = __fsub_rn(dz, c2);

    d2 = __fadd_rn(__fadd_rn(__fmul_rn(dx, dx), __fmul_rn(dy, dy)), __fmul_rn(dz, dz));
}

// Diagonal-box fast path: same values as the general path when all
// off-diagonal box entries are zero (cross terms are +-0; dropping them can
// only flip sign of an exact zero, which d2 and the wrap subtraction erase).
__device__ __forceinline__ void min_image_diag(float xi, float yi, float zi,
                                               float xj, float yj, float zj,
                                               float b0, float b1, float b2,
                                               float ib0, float ib1, float ib2,
                                               float& dx, float& dy, float& dz, float& d2) {
    dx = __fsub_rn(xi, xj);
    dy = __fsub_rn(yi, yj);
    dz = __fsub_rn(zi, zj);
    float r0 = rintf(__fmul_rn(dx, ib0));
    float r1 = rintf(__fmul_rn(dy, ib1));
    float r2 = rintf(__fmul_rn(dz, ib2));
    dx = __fsub_rn(dx, __fmul_rn(r0, b0));
    dy = __fsub_rn(dy, __fmul_rn(r1, b1));
    dz = __fsub_rn(dz, __fmul_rn(r2, b2));
    d2 = __fadd_rn(__fadd_rn(__fmul_rn(dx, dx), __fmul_rn(dy, dy)), __fmul_rn(dz, dz));
}

// K0: transpose positions [N,3] AoS -> SoA X/Y/Z (exact copy, no math).
__global__ void __launch_bounds__(256)
k0_transpose(const float* __restrict__ pos,
             float* __restrict__ X, float* __restrict__ Y, float* __restrict__ Z,
             int N) {
    int idx = blockIdx.x * blockDim.x + threadIdx.x;
    if (idx < N) {
        X[idx] = pos[3 * idx + 0];
        Y[idx] = pos[3 * idx + 1];
        Z[idx] = pos[3 * idx + 2];
    }
}

// Count hits for row i (j > i) from SoA; write per-chunk masks to mrow[].
template <bool DIAG>
__device__ __forceinline__ int count_row(int i, int lane,
                                         const float* __restrict__ X,
                                         const float* __restrict__ Y,
                                         const float* __restrict__ Z,
                                         const float B[3][3], const float Binv[3][3],
                                         unsigned long long* __restrict__ mrow,
                                         int nchunks) {
    float xi = X[i], yi = Y[i], zi = Z[i];
    float b0 = B[0][0], b1 = B[1][1], b2 = B[2][2];
    float ib0 = Binv[0][0], ib1 = Binv[1][1], ib2 = Binv[2][2];
    int c0 = i >> 6;
    int cnt = 0;

    // Diagonal chunk: needs the j>i predicate.
    {
        int j = (c0 << 6) + lane;
        bool hit = false;
        if (j > i) {
            float dx, dy, dz, d2;
            if (DIAG)
                min_image_diag(xi, yi, zi, X[j], Y[j], Z[j],
                               b0, b1, b2, ib0, ib1, ib2, dx, dy, dz, d2);
            else
                min_image(xi, yi, zi, X[j], Y[j], Z[j], B, Binv, dx, dy, dz, d2);
            hit = (d2 < CUT2);
        }
        unsigned long long m = __ballot(hit);
        if (lane == 0) mrow[c0] = m;
        cnt += __popcll(m);
    }

    // Remaining chunks: all j > i. Unroll x4 for ILP.
    int c = c0 + 1;
    for (; c + 4 <= nchunks; c += 4) {
        int j0 = (c << 6) + lane;
        float dx0, dy0, dz0, d20, dx1, dy1, dz1, d21;
        float dx2, dy2, dz2, d22, dx3, dy3, dz3, d23;
        if (DIAG) {
            min_image_diag(xi, yi, zi, X[j0 +   0], Y[j0 +   0], Z[j0 +   0], b0, b1, b2, ib0, ib1, ib2, dx0, dy0, dz0, d20);
            min_image_diag(xi, yi, zi, X[j0 +  64], Y[j0 +  64], Z[j0 +  64], b0, b1, b2, ib0, ib1, ib2, dx1, dy1, dz1, d21);
            min_image_diag(xi, yi, zi, X[j0 + 128], Y[j0 + 128], Z[j0 + 128], b0, b1, b2, ib0, ib1, ib2, dx2, dy2, dz2, d22);
            min_image_diag(xi, yi, zi, X[j0 + 192], Y[j0 + 192], Z[j0 + 192], b0, b1, b2, ib0, ib1, ib2, dx3, dy3, dz3, d23);
        } else {
            min_image(xi, yi, zi, X[j0 +   0], Y[j0 +   0], Z[j0 +   0], B, Binv, dx0, dy0, dz0, d20);
            min_image(xi, yi, zi, X[j0 +  64], Y[j0 +  64], Z[j0 +  64], B, Binv, dx1, dy1, dz1, d21);
            min_image(xi, yi, zi, X[j0 + 128], Y[j0 + 128], Z[j0 + 128], B, Binv, dx2, dy2, dz2, d22);
            min_image(xi, yi, zi, X[j0 + 192], Y[j0 + 192], Z[j0 + 192], B, Binv, dx3, dy3, dz3, d23);
        }
        unsigned long long m0 = __ballot(d20 < CUT2);
        unsigned long long m1 = __ballot(d21 < CUT2);
        unsigned long long m2 = __ballot(d22 < CUT2);
        unsigned long long m3 = __ballot(d23 < CUT2);
        if (lane == 0) { mrow[c] = m0; mrow[c + 1] = m1; mrow[c + 2] = m2; mrow[c + 3] = m3; }
        cnt += __popcll(m0) + __popcll(m1) + __popcll(m2) + __popcll(m3);
    }
    for (; c < nchunks; ++c) {
        int j = (c << 6) + lane;
        float dx, dy, dz, d2;
        if (DIAG)
            min_image_diag(xi, yi, zi, X[j], Y[j], Z[j],
                           b0, b1, b2, ib0, ib1, ib2, dx, dy, dz, d2);
        else
            min_image(xi, yi, zi, X[j], Y[j], Z[j], B, Binv, dx, dy, dz, d2);
        unsigned long long m = __ballot(d2 < CUT2);
        if (lane == 0) mrow[c] = m;
        cnt += __popcll(m);
    }
    return cnt;
}

// K1: pad output + count one row per wave + write masks.
__global__ void __launch_bounds__(256)
k1_pad_count(const float* __restrict__ X, const float* __restrict__ Y,
             const float* __restrict__ Z, const float* __restrict__ box,
             float* __restrict__ out, int* __restrict__ counts,
             unsigned long long* __restrict__ masks, int N, int P) {
    int tid = blockIdx.x * blockDim.x + threadIdx.x;
    int nthreads = gridDim.x * blockDim.x;   // N*64

    // pad: pairs = -1, rest = 0 (stores retire while we compute)
    int total = 6 * P + 1;
    for (int k = tid; k < total; k += nthreads)
        out[k] = (k < 2 * P) ? -1.0f : 0.0f;

    int i = tid >> 6;
    int lane = tid & 63;
    int nchunks = N >> 6;

    float B[3][3], Binv[3][3];
    load_box_inv(box, B, Binv);
    bool diag = (B[0][1] == 0.0f) & (B[0][2] == 0.0f) & (B[1][0] == 0.0f) &
                (B[1][2] == 0.0f) & (B[2][0] == 0.0f) & (B[2][1] == 0.0f);

    int cnt;
    if (diag)
        cnt = count_row<true>(i, lane, X, Y, Z, B, Binv,
                              masks + (size_t)i * nchunks, nchunks);
    else
        cnt = count_row<false>(i, lane, X, Y, Z, B, Binv,
                               masks + (size_t)i * nchunks, nchunks);
    if (lane == 0) counts[i] = cnt;
}

// K2: one wave per row. int4 prefix over counts[0..i), then ordered fill of
// hits from the precomputed masks (general math path, SoA gathers).
__global__ void __launch_bounds__(256)
k2_scan_fill(const float* __restrict__ X, const float* __restrict__ Y,
             const float* __restrict__ Z, const float* __restrict__ box,
             const int* __restrict__ counts,
             const unsigned long long* __restrict__ masks,
             float* __restrict__ out, int N, int P) {
    int tid = blockIdx.x * blockDim.x + threadIdx.x;
    int i = tid >> 6;
    int lane = tid & 63;
    int nchunks = N >> 6;
    int c0 = i >> 6;

    // Exclusive prefix over counts[0..i) via int4 loads + butterfly.
    int pre = 0;
    for (int base = 0; base < i; base += 256) {
        int idx = base + 4 * lane;
        int4 v = *(const int4*)(counts + idx);   // may read past i; masked below
        if (idx + 0 < i) pre += v.x;
        if (idx + 1 < i) pre += v.y;
        if (idx + 2 < i) pre += v.z;
        if (idx + 3 < i) pre += v.w;
    }
    #pragma unroll
    for (int d = 1; d < 64; d <<= 1)
        pre += __shfl_xor(pre, d);               // all lanes: sum counts[0..i)

    if (i == N - 1 && lane == 0)
        out[6 * (size_t)P] = (float)(pre + counts[i]);   // n_pairs

    // lane l holds the mask of chunk l for this row (only cc >= c0 consumed).
    unsigned long long mymask = masks[(size_t)i * nchunks + lane];

    float B[3][3], Binv[3][3];
    load_box_inv(box, B, Binv);
    float xi = X[i], yi = Y[i], zi = Z[i];

    int base = pre;
    for (int cc = c0; cc < nchunks; ++cc) {
        unsigned long long m = __shfl(mymask, cc);
        if (m != 0ull) {
            if ((m >> lane) & 1ull) {
                int j = (cc << 6) + lane;
                float dx, dy, dz, d2;
                min_image(xi, yi, zi, X[j], Y[j], Z[j], B, Binv, dx, dy, dz, d2);
                int slot = base + __popcll(m & ((1ull << lane) - 1ull));
                if (slot < P) {
                    out[slot] = (float)i;                    // pair_i
                    out[P + slot] = (float)j;                // pair_j
                    size_t db = 2 * (size_t)P + 3 * (size_t)slot;
                    out[db + 0] = dx;
                    out[db + 1] = dy;
                    out[db + 2] = dz;
                    out[5 * (size_t)P + slot] = sqrtf(d2);   // distance
                }
            }
            base += __popcll(m);
        }
    }
}

extern "C" void kernel_launch(void* const* d_in, const int* in_sizes, int n_in,
                              void* d_out, int out_size, void* d_ws, size_t ws_size,
                              hipStream_t stream) {
    const float* pos = (const float*)d_in[0];
    const float* box = (const float*)d_in[1];
    float* out = (float*)d_out;

    int N = in_sizes[0] / 3;          // 4096
    int P = (out_size - 1) / 6;       // 131072
    int nchunks = N >> 6;

    // ws layout: X[N] | Y[N] | Z[N] | counts[N] | masks[N*nchunks]
    char* w = (char*)d_ws;
    float* X = (float*)w;                          w += (size_t)N * sizeof(float);
    float* Y = (float*)w;                          w += (size_t)N * sizeof(float);
    float* Z = (float*)w;                          w += (size_t)N * sizeof(float);
    int* counts = (int*)w;                         w += (size_t)N * sizeof(int);
    unsigned long long* masks = (unsigned long long*)w;

    // K0: AoS -> SoA transpose (tiny).
    k0_transpose<<<(N + 255) / 256, 256, 0, stream>>>(pos, X, Y, Z, N);

    // K1: one wave per row -> N/4 blocks of 256.
    k1_pad_count<<<N / 4, 256, 0, stream>>>(X, Y, Z, box, out, counts, masks, N, P);

    // K2: one wave per row -> N/4 blocks of 256.
    k2_scan_fill<<<N / 4, 256, 0, stream>>>(X, Y, Z, box, counts, masks, out, N, P);
}